// Round 1
// baseline (177.126 us; speedup 1.0000x reference)
//
#include <hip/hip_runtime.h>
#include <hip/hip_bf16.h>
#include <math.h>

#define EPSF 1e-6f

// ---------------------------------------------------------------------------
// Kernel A: bucket means for q and k.
// grid.x = 4096: [tensor(2)][bh(32)][bucket(64)], block = 256 threads.
// Each block reduces 128 rows x 64 dims (32 KB) -> 64 floats.
// ---------------------------------------------------------------------------
__global__ __launch_bounds__(256) void bucket_mean_kernel(
    const float* __restrict__ q,
    const float* __restrict__ k,
    float* __restrict__ sqk)  // [2][32][64][64]
{
    int b      = blockIdx.x;
    int t      = b >> 11;        // 0 = q, 1 = k
    int rem    = b & 2047;
    int bh     = rem >> 6;
    int bucket = rem & 63;

    const float* src = t ? k : q;
    const float4* base = reinterpret_cast<const float4*>(
        src + ((size_t)bh * 8192 + (size_t)bucket * 128) * 64);

    int c  = threadIdx.x & 15;   // float4 column (0..15)
    int rr = threadIdx.x >> 4;   // row group    (0..15)

    float4 acc = make_float4(0.f, 0.f, 0.f, 0.f);
    #pragma unroll
    for (int j = rr; j < 128; j += 16) {
        float4 v = base[j * 16 + c];
        acc.x += v.x; acc.y += v.y; acc.z += v.z; acc.w += v.w;
    }

    __shared__ float4 red[256];
    red[threadIdx.x] = acc;
    __syncthreads();

    // reduce over the 16 row-groups (partner stride 16 in tid)
    #pragma unroll
    for (int s = 128; s >= 16; s >>= 1) {
        if (threadIdx.x < (unsigned)s) {
            float4 o = red[threadIdx.x + s];
            float4 m = red[threadIdx.x];
            m.x += o.x; m.y += o.y; m.z += o.z; m.w += o.w;
            red[threadIdx.x] = m;
        }
        __syncthreads();
    }

    if (threadIdx.x < 16) {
        float4 m = red[threadIdx.x];
        const float inv = 1.0f / 128.0f;
        m.x *= inv; m.y *= inv; m.z *= inv; m.w *= inv;
        float4* dst = reinterpret_cast<float4*>(
            sqk + (size_t)t * 32 * 64 * 64 + ((size_t)bh * 64 + bucket) * 64);
        dst[threadIdx.x] = m;
    }
}

// ---------------------------------------------------------------------------
// Kernel B: per-bh  R = sq·sk^T/8, gumbel perturb, 8 sinkhorn iters, exp.
// grid.x = 32 (one block per bh), block = 256 threads.
// ---------------------------------------------------------------------------
__global__ __launch_bounds__(256) void sinkhorn_kernel(
    const float* __restrict__ sqk,      // [2][32][64][64]
    const float* __restrict__ u_gumbel, // [32][64][64]
    float* __restrict__ out)            // [32][64][64]
{
    int bh = blockIdx.x;

    __shared__ float sq_s[64][65];
    __shared__ float sk_s[64][65];
    __shared__ float r_s[64][65];

    const float* sqp = sqk + (size_t)bh * 4096;
    const float* skp = sqk + (size_t)32 * 4096 + (size_t)bh * 4096;

    #pragma unroll
    for (int t = 0; t < 16; ++t) {
        int idx = threadIdx.x + 256 * t;
        int i = idx >> 6, e = idx & 63;
        sq_s[i][e] = sqp[idx];
        sk_s[i][e] = skp[idx];
    }
    __syncthreads();

    // R = sq·sk^T * 64^-0.5 ; r = (log(relu(R)+eps) + gumbel) / T
    const float scale = 0.125f;          // 64^-0.5
    const float invT  = 1.0f / 0.7f;
    #pragma unroll 4
    for (int t = 0; t < 16; ++t) {
        int idx = threadIdx.x + 256 * t;
        int i = idx >> 6, j = idx & 63;
        float acc = 0.f;
        #pragma unroll
        for (int e = 0; e < 64; ++e)
            acc = fmaf(sq_s[i][e], sk_s[j][e], acc);
        float R  = acc * scale;
        float rl = fmaxf(R, 0.f);
        float u  = u_gumbel[(size_t)bh * 4096 + idx];
        float g  = -logf(-logf(u + EPSF) + EPSF);
        r_s[i][j] = (logf(rl + EPSF) + g) * invT;
    }
    __syncthreads();

    // Sinkhorn: 8 x (col-normalize over j [axis=2], then over i [axis=1]).
    // 4 lanes cooperate per row/col; lanes of a group are adjacent -> shfl_xor.
    int lane4 = threadIdx.x & 3;
    int rc    = threadIdx.x >> 2;   // row (or col) index, 0..63
    for (int it = 0; it < 8; ++it) {
        {   // axis=2: LSE over j within row rc
            float m = -INFINITY;
            #pragma unroll
            for (int t = 0; t < 16; ++t) m = fmaxf(m, r_s[rc][lane4 * 16 + t]);
            m = fmaxf(m, __shfl_xor(m, 1, 64));
            m = fmaxf(m, __shfl_xor(m, 2, 64));
            float s = 0.f;
            #pragma unroll
            for (int t = 0; t < 16; ++t) s += expf(r_s[rc][lane4 * 16 + t] - m);
            s += __shfl_xor(s, 1, 64);
            s += __shfl_xor(s, 2, 64);
            float lse = m + logf(s);
            #pragma unroll
            for (int t = 0; t < 16; ++t) r_s[rc][lane4 * 16 + t] -= lse;
        }
        __syncthreads();
        {   // axis=1: LSE over i within column rc
            float m = -INFINITY;
            #pragma unroll
            for (int t = 0; t < 16; ++t) m = fmaxf(m, r_s[lane4 * 16 + t][rc]);
            m = fmaxf(m, __shfl_xor(m, 1, 64));
            m = fmaxf(m, __shfl_xor(m, 2, 64));
            float s = 0.f;
            #pragma unroll
            for (int t = 0; t < 16; ++t) s += expf(r_s[lane4 * 16 + t][rc] - m);
            s += __shfl_xor(s, 1, 64);
            s += __shfl_xor(s, 2, 64);
            float lse = m + logf(s);
            #pragma unroll
            for (int t = 0; t < 16; ++t) r_s[lane4 * 16 + t][rc] -= lse;
        }
        __syncthreads();
    }

    // out = exp(r)
    #pragma unroll
    for (int t = 0; t < 16; ++t) {
        int idx = threadIdx.x + 256 * t;
        int i = idx >> 6, j = idx & 63;
        out[(size_t)bh * 4096 + idx] = expf(r_s[i][j]);
    }
}

extern "C" void kernel_launch(void* const* d_in, const int* in_sizes, int n_in,
                              void* d_out, int out_size, void* d_ws, size_t ws_size,
                              hipStream_t stream) {
    const float* q = (const float*)d_in[0];        // [32,8192,64]
    const float* k = (const float*)d_in[1];        // [32,8192,64]
    const float* u = (const float*)d_in[2];        // [32,64,64]
    float* out = (float*)d_out;                    // [32,64,64]
    float* sqk = (float*)d_ws;                     // [2][32][64][64] = 1 MiB

    bucket_mean_kernel<<<4096, 256, 0, stream>>>(q, k, sqk);
    sinkhorn_kernel<<<32, 256, 0, stream>>>(sqk, u, out);
}

// Round 3
// 166.474 us; speedup vs baseline: 1.0640x; 1.0640x over previous
//
#include <hip/hip_runtime.h>
#include <hip/hip_bf16.h>
#include <math.h>

#define EPSF 1e-6f

// ---------------------------------------------------------------------------
// Kernel A: bucket means for q and k. One WAVE per (tensor, bh, bucket):
// 4096 waves -> 1024 blocks x 256. No LDS, no barriers.
// Lane layout: rr = lane>>4 (row group 0..3), c = lane&15 (float4 column).
// Each lane: 32 float4 loads (wave reads 4 rows = 1KB per instr, coalesced),
// then shfl_xor(16,32) reduce across row groups; lanes 0-15 store.
// ---------------------------------------------------------------------------
__global__ __launch_bounds__(256) void bucket_mean_kernel(
    const float* __restrict__ q,
    const float* __restrict__ k,
    float* __restrict__ sqk)  // [2][32][64][64]
{
    int g      = blockIdx.x * 4 + (threadIdx.x >> 6);
    int t      = g >> 11;        // 0 = q, 1 = k
    int bh     = (g >> 6) & 31;
    int bucket = g & 63;

    const float* src = t ? k : q;
    const float4* base = reinterpret_cast<const float4*>(
        src + ((size_t)bh * 8192 + (size_t)bucket * 128) * 64);

    int lane = threadIdx.x & 63;
    int rr   = lane >> 4;        // 0..3
    int c    = lane & 15;        // 0..15

    float4 acc = make_float4(0.f, 0.f, 0.f, 0.f);
    #pragma unroll 8
    for (int j = 0; j < 32; ++j) {
        float4 v = base[(rr + j * 4) * 16 + c];
        acc.x += v.x; acc.y += v.y; acc.z += v.z; acc.w += v.w;
    }

    // reduce across the 4 row groups (lane bits 4,5)
    acc.x += __shfl_xor(acc.x, 16, 64);
    acc.y += __shfl_xor(acc.y, 16, 64);
    acc.z += __shfl_xor(acc.z, 16, 64);
    acc.w += __shfl_xor(acc.w, 16, 64);
    acc.x += __shfl_xor(acc.x, 32, 64);
    acc.y += __shfl_xor(acc.y, 32, 64);
    acc.z += __shfl_xor(acc.z, 32, 64);
    acc.w += __shfl_xor(acc.w, 32, 64);

    if (lane < 16) {
        const float inv = 1.0f / 128.0f;
        acc.x *= inv; acc.y *= inv; acc.z *= inv; acc.w *= inv;
        float4* dst = reinterpret_cast<float4*>(
            sqk + (size_t)t * 32 * 64 * 64 + ((size_t)bh * 64 + bucket) * 64);
        dst[c] = acc;
    }
}

// ---------------------------------------------------------------------------
// Kernel B: per-bh  R = sq·sk^T/8, gumbel perturb, 8 sinkhorn iters, exp.
// grid.x = 32 (one block per bh), block = 1024 threads (4 elems/thread).
// ---------------------------------------------------------------------------
__global__ __launch_bounds__(1024) void sinkhorn_kernel(
    const float* __restrict__ sqk,      // [2][32][64][64]
    const float* __restrict__ u_gumbel, // [32][64][64]
    float* __restrict__ out)            // [32][64][64]
{
    int bh  = blockIdx.x;
    int tid = threadIdx.x;

    __shared__ float sq_s[64][65];
    __shared__ float sk_s[64][65];
    __shared__ float r_s[64][65];

    const float* sqp = sqk + (size_t)bh * 4096;
    const float* skp = sqk + (size_t)32 * 4096 + (size_t)bh * 4096;

    #pragma unroll
    for (int t = 0; t < 4; ++t) {
        int idx = tid + 1024 * t;
        int i = idx >> 6, e = idx & 63;
        sq_s[i][e] = sqp[idx];
        sk_s[i][e] = skp[idx];
    }
    __syncthreads();

    // R rows: within a wave i is uniform (sq read = broadcast), j = lane.
    // Thread computes rows i = (tid>>6) + 16t, column j = tid&63.
    {
        int j  = tid & 63;
        int i0 = tid >> 6;            // 0..15
        float acc0 = 0.f, acc1 = 0.f, acc2 = 0.f, acc3 = 0.f;
        #pragma unroll
        for (int e = 0; e < 64; ++e) {
            float s = sk_s[j][e];     // lanes hit banks (j+e)%32: 2-way, free
            acc0 = fmaf(sq_s[i0][e],      s, acc0);
            acc1 = fmaf(sq_s[i0 + 16][e], s, acc1);
            acc2 = fmaf(sq_s[i0 + 32][e], s, acc2);
            acc3 = fmaf(sq_s[i0 + 48][e], s, acc3);
        }
        const float scale = 0.125f;   // 64^-0.5
        const float invT  = 1.0f / 0.7f;
        float accs[4] = {acc0, acc1, acc2, acc3};
        #pragma unroll
        for (int t = 0; t < 4; ++t) {
            int i   = i0 + 16 * t;
            float R = accs[t] * scale;
            float rl = fmaxf(R, 0.f);
            float u  = u_gumbel[(size_t)bh * 4096 + i * 64 + j];
            float gm = -__logf(-__logf(u + EPSF) + EPSF);
            r_s[i][j] = (__logf(rl + EPSF) + gm) * invT;
        }
    }
    __syncthreads();

    // Sinkhorn: 8 x (LSE-normalize axis=2 rows, then axis=1 cols).
    // 16 lanes per row/col; thread owns 4 consecutive elems (lane16*4+t):
    // banks (rc + 4*lane16 + t)%32 -> 2-way, free. Shuffle groups xor 1,2,4,8.
    int lane16 = tid & 15;
    int rc     = tid >> 4;            // 0..63
    int cbase  = lane16 * 4;
    for (int it = 0; it < 8; ++it) {
        {   // axis=2: LSE over j within row rc
            float v0 = r_s[rc][cbase + 0], v1 = r_s[rc][cbase + 1];
            float v2 = r_s[rc][cbase + 2], v3 = r_s[rc][cbase + 3];
            float m = fmaxf(fmaxf(v0, v1), fmaxf(v2, v3));
            m = fmaxf(m, __shfl_xor(m, 1, 64));
            m = fmaxf(m, __shfl_xor(m, 2, 64));
            m = fmaxf(m, __shfl_xor(m, 4, 64));
            m = fmaxf(m, __shfl_xor(m, 8, 64));
            float s = __expf(v0 - m) + __expf(v1 - m)
                    + __expf(v2 - m) + __expf(v3 - m);
            s += __shfl_xor(s, 1, 64);
            s += __shfl_xor(s, 2, 64);
            s += __shfl_xor(s, 4, 64);
            s += __shfl_xor(s, 8, 64);
            float lse = m + __logf(s);
            r_s[rc][cbase + 0] = v0 - lse;
            r_s[rc][cbase + 1] = v1 - lse;
            r_s[rc][cbase + 2] = v2 - lse;
            r_s[rc][cbase + 3] = v3 - lse;
        }
        __syncthreads();
        {   // axis=1: LSE over i within column rc
            float v0 = r_s[cbase + 0][rc], v1 = r_s[cbase + 1][rc];
            float v2 = r_s[cbase + 2][rc], v3 = r_s[cbase + 3][rc];
            float m = fmaxf(fmaxf(v0, v1), fmaxf(v2, v3));
            m = fmaxf(m, __shfl_xor(m, 1, 64));
            m = fmaxf(m, __shfl_xor(m, 2, 64));
            m = fmaxf(m, __shfl_xor(m, 4, 64));
            m = fmaxf(m, __shfl_xor(m, 8, 64));
            float s = __expf(v0 - m) + __expf(v1 - m)
                    + __expf(v2 - m) + __expf(v3 - m);
            s += __shfl_xor(s, 1, 64);
            s += __shfl_xor(s, 2, 64);
            s += __shfl_xor(s, 4, 64);
            s += __shfl_xor(s, 8, 64);
            float lse = m + __logf(s);
            r_s[cbase + 0][rc] = v0 - lse;
            r_s[cbase + 1][rc] = v1 - lse;
            r_s[cbase + 2][rc] = v2 - lse;
            r_s[cbase + 3][rc] = v3 - lse;
        }
        __syncthreads();
    }

    // out = exp(r)
    #pragma unroll
    for (int t = 0; t < 4; ++t) {
        int idx = tid + 1024 * t;
        out[(size_t)bh * 4096 + idx] = __expf(r_s[idx >> 6][idx & 63]);
    }
}

extern "C" void kernel_launch(void* const* d_in, const int* in_sizes, int n_in,
                              void* d_out, int out_size, void* d_ws, size_t ws_size,
                              hipStream_t stream) {
    const float* q = (const float*)d_in[0];        // [32,8192,64]
    const float* k = (const float*)d_in[1];        // [32,8192,64]
    const float* u = (const float*)d_in[2];        // [32,64,64]
    float* out = (float*)d_out;                    // [32,64,64]
    float* sqk = (float*)d_ws;                     // [2][32][64][64] = 1 MiB

    bucket_mean_kernel<<<1024, 256, 0, stream>>>(q, k, sqk);
    sinkhorn_kernel<<<32, 1024, 0, stream>>>(sqk, u, out);
}

// Round 5
// 158.847 us; speedup vs baseline: 1.1151x; 1.0480x over previous
//
#include <hip/hip_runtime.h>
#include <hip/hip_bf16.h>
#include <math.h>

#define EPSF 1e-6f

// clang native vector type — required by __builtin_nontemporal_load
typedef float float4n __attribute__((ext_vector_type(4)));

// ---------------------------------------------------------------------------
// Kernel A: bucket means for q and k. One WAVE per (tensor, bh, bucket):
// 4096 waves -> 1024 blocks x 256. No LDS, no barriers.
// Lane layout: rr = lane>>4 (row group 0..3), c = lane&15 (float4 column).
// Each lane: 32 nontemporal float4 loads, batched 8-deep (explicit temps so
// 8 loads stay in flight), then shfl_xor(16,32) reduce across row groups.
// ---------------------------------------------------------------------------
__global__ __launch_bounds__(256) void bucket_mean_kernel(
    const float* __restrict__ q,
    const float* __restrict__ k,
    float* __restrict__ sqk)  // [2][32][64][64]
{
    int g      = blockIdx.x * 4 + (threadIdx.x >> 6);
    int t      = g >> 11;        // 0 = q, 1 = k
    int bh     = (g >> 6) & 31;
    int bucket = g & 63;

    const float* src = t ? k : q;
    const float4n* base = reinterpret_cast<const float4n*>(
        src + ((size_t)bh * 8192 + (size_t)bucket * 128) * 64);

    int lane = threadIdx.x & 63;
    int rr   = lane >> 4;        // 0..3
    int c    = lane & 15;        // 0..15

    float4n acc = (float4n)(0.f);
    #pragma unroll
    for (int b = 0; b < 4; ++b) {
        float4n v0 = __builtin_nontemporal_load(&base[(rr + (b * 8 + 0) * 4) * 16 + c]);
        float4n v1 = __builtin_nontemporal_load(&base[(rr + (b * 8 + 1) * 4) * 16 + c]);
        float4n v2 = __builtin_nontemporal_load(&base[(rr + (b * 8 + 2) * 4) * 16 + c]);
        float4n v3 = __builtin_nontemporal_load(&base[(rr + (b * 8 + 3) * 4) * 16 + c]);
        float4n v4 = __builtin_nontemporal_load(&base[(rr + (b * 8 + 4) * 4) * 16 + c]);
        float4n v5 = __builtin_nontemporal_load(&base[(rr + (b * 8 + 5) * 4) * 16 + c]);
        float4n v6 = __builtin_nontemporal_load(&base[(rr + (b * 8 + 6) * 4) * 16 + c]);
        float4n v7 = __builtin_nontemporal_load(&base[(rr + (b * 8 + 7) * 4) * 16 + c]);
        acc += v0 + v1 + v2 + v3 + v4 + v5 + v6 + v7;
    }

    // reduce across the 4 row groups (lane bits 4,5)
    acc.x += __shfl_xor(acc.x, 16, 64);
    acc.y += __shfl_xor(acc.y, 16, 64);
    acc.z += __shfl_xor(acc.z, 16, 64);
    acc.w += __shfl_xor(acc.w, 16, 64);
    acc.x += __shfl_xor(acc.x, 32, 64);
    acc.y += __shfl_xor(acc.y, 32, 64);
    acc.z += __shfl_xor(acc.z, 32, 64);
    acc.w += __shfl_xor(acc.w, 32, 64);

    if (lane < 16) {
        acc *= (1.0f / 128.0f);
        float4n* dst = reinterpret_cast<float4n*>(
            sqk + (size_t)t * 32 * 64 * 64 + ((size_t)bh * 64 + bucket) * 64);
        dst[c] = acc;
    }
}

// ---------------------------------------------------------------------------
// Kernel B: per-bh  R = sq·sk^T/8, gumbel perturb, 8 sinkhorn iters, exp.
// grid.x = 32 (one block per bh), block = 1024 threads (4 elems/thread).
// ---------------------------------------------------------------------------
__global__ __launch_bounds__(1024) void sinkhorn_kernel(
    const float* __restrict__ sqk,      // [2][32][64][64]
    const float* __restrict__ u_gumbel, // [32][64][64]
    float* __restrict__ out)            // [32][64][64]
{
    int bh  = blockIdx.x;
    int tid = threadIdx.x;

    __shared__ float sq_s[64][65];
    __shared__ float sk_s[64][65];
    __shared__ float r_s[64][65];

    const float* sqp = sqk + (size_t)bh * 4096;
    const float* skp = sqk + (size_t)32 * 4096 + (size_t)bh * 4096;

    #pragma unroll
    for (int t = 0; t < 4; ++t) {
        int idx = tid + 1024 * t;
        int i = idx >> 6, e = idx & 63;
        sq_s[i][e] = sqp[idx];
        sk_s[i][e] = skp[idx];
    }
    __syncthreads();

    // R rows: within a wave i is uniform (sq read = broadcast), j = lane.
    // Thread computes rows i = (tid>>6) + 16t, column j = tid&63.
    {
        int j  = tid & 63;
        int i0 = tid >> 6;            // 0..15
        float acc0 = 0.f, acc1 = 0.f, acc2 = 0.f, acc3 = 0.f;
        #pragma unroll
        for (int e = 0; e < 64; ++e) {
            float s = sk_s[j][e];     // lanes hit banks (j+e)%32: 2-way, free
            acc0 = fmaf(sq_s[i0][e],      s, acc0);
            acc1 = fmaf(sq_s[i0 + 16][e], s, acc1);
            acc2 = fmaf(sq_s[i0 + 32][e], s, acc2);
            acc3 = fmaf(sq_s[i0 + 48][e], s, acc3);
        }
        const float scale = 0.125f;   // 64^-0.5
        const float invT  = 1.0f / 0.7f;
        float accs[4] = {acc0, acc1, acc2, acc3};
        #pragma unroll
        for (int t = 0; t < 4; ++t) {
            int i   = i0 + 16 * t;
            float R = accs[t] * scale;
            float rl = fmaxf(R, 0.f);
            float u  = u_gumbel[(size_t)bh * 4096 + i * 64 + j];
            float gm = -__logf(-__logf(u + EPSF) + EPSF);
            r_s[i][j] = (__logf(rl + EPSF) + gm) * invT;
        }
    }
    __syncthreads();

    // Sinkhorn: 8 x (LSE-normalize axis=2 rows, then axis=1 cols).
    // 16 lanes per row/col; thread owns 4 consecutive elems (lane16*4+t):
    // banks (rc + 4*lane16 + t)%32 -> 2-way, free. Shuffle groups xor 1,2,4,8.
    int lane16 = tid & 15;
    int rc     = tid >> 4;            // 0..63
    int cbase  = lane16 * 4;
    for (int it = 0; it < 8; ++it) {
        {   // axis=2: LSE over j within row rc
            float v0 = r_s[rc][cbase + 0], v1 = r_s[rc][cbase + 1];
            float v2 = r_s[rc][cbase + 2], v3 = r_s[rc][cbase + 3];
            float m = fmaxf(fmaxf(v0, v1), fmaxf(v2, v3));
            m = fmaxf(m, __shfl_xor(m, 1, 64));
            m = fmaxf(m, __shfl_xor(m, 2, 64));
            m = fmaxf(m, __shfl_xor(m, 4, 64));
            m = fmaxf(m, __shfl_xor(m, 8, 64));
            float s = __expf(v0 - m) + __expf(v1 - m)
                    + __expf(v2 - m) + __expf(v3 - m);
            s += __shfl_xor(s, 1, 64);
            s += __shfl_xor(s, 2, 64);
            s += __shfl_xor(s, 4, 64);
            s += __shfl_xor(s, 8, 64);
            float lse = m + __logf(s);
            r_s[rc][cbase + 0] = v0 - lse;
            r_s[rc][cbase + 1] = v1 - lse;
            r_s[rc][cbase + 2] = v2 - lse;
            r_s[rc][cbase + 3] = v3 - lse;
        }
        __syncthreads();
        {   // axis=1: LSE over i within column rc
            float v0 = r_s[cbase + 0][rc], v1 = r_s[cbase + 1][rc];
            float v2 = r_s[cbase + 2][rc], v3 = r_s[cbase + 3][rc];
            float m = fmaxf(fmaxf(v0, v1), fmaxf(v2, v3));
            m = fmaxf(m, __shfl_xor(m, 1, 64));
            m = fmaxf(m, __shfl_xor(m, 2, 64));
            m = fmaxf(m, __shfl_xor(m, 4, 64));
            m = fmaxf(m, __shfl_xor(m, 8, 64));
            float s = __expf(v0 - m) + __expf(v1 - m)
                    + __expf(v2 - m) + __expf(v3 - m);
            s += __shfl_xor(s, 1, 64);
            s += __shfl_xor(s, 2, 64);
            s += __shfl_xor(s, 4, 64);
            s += __shfl_xor(s, 8, 64);
            float lse = m + __logf(s);
            r_s[cbase + 0][rc] = v0 - lse;
            r_s[cbase + 1][rc] = v1 - lse;
            r_s[cbase + 2][rc] = v2 - lse;
            r_s[cbase + 3][rc] = v3 - lse;
        }
        __syncthreads();
    }

    // out = exp(r)
    #pragma unroll
    for (int t = 0; t < 4; ++t) {
        int idx = tid + 1024 * t;
        out[(size_t)bh * 4096 + idx] = __expf(r_s[idx >> 6][idx & 63]);
    }
}

extern "C" void kernel_launch(void* const* d_in, const int* in_sizes, int n_in,
                              void* d_out, int out_size, void* d_ws, size_t ws_size,
                              hipStream_t stream) {
    const float* q = (const float*)d_in[0];        // [32,8192,64]
    const float* k = (const float*)d_in[1];        // [32,8192,64]
    const float* u = (const float*)d_in[2];        // [32,64,64]
    float* out = (float*)d_out;                    // [32,64,64]
    float* sqk = (float*)d_ws;                     // [2][32][64][64] = 1 MiB

    bucket_mean_kernel<<<1024, 256, 0, stream>>>(q, k, sqk);
    sinkhorn_kernel<<<32, 1024, 0, stream>>>(sqk, u, out);
}

// Round 7
// 158.317 us; speedup vs baseline: 1.1188x; 1.0033x over previous
//
#include <hip/hip_runtime.h>
#include <hip/hip_bf16.h>
#include <math.h>

#define EPSF 1e-6f

// clang native vector type — required by __builtin_nontemporal_load
typedef float float4n __attribute__((ext_vector_type(4)));

__device__ inline float readlane_f(float v, int l) {
    return __int_as_float(__builtin_amdgcn_readlane(__float_as_int(v), l));
}

// ---------------------------------------------------------------------------
// Kernel A: bucket means for q and k. One WAVE per (tensor, bh, bucket):
// 4096 waves -> 1024 blocks x 256. No LDS, no barriers.
// Each lane: 32 nontemporal float4 loads in 2 batches of 16 (16 loads in
// flight, ~8 KB/lane-group outstanding), then shfl_xor(16,32) reduce.
// ---------------------------------------------------------------------------
__global__ __launch_bounds__(256) void bucket_mean_kernel(
    const float* __restrict__ q,
    const float* __restrict__ k,
    float* __restrict__ sqk)  // [2][32][64][64]
{
    int g      = blockIdx.x * 4 + (threadIdx.x >> 6);
    int t      = g >> 11;        // 0 = q, 1 = k
    int bh     = (g >> 6) & 31;
    int bucket = g & 63;

    const float* src = t ? k : q;
    const float4n* base = reinterpret_cast<const float4n*>(
        src + ((size_t)bh * 8192 + (size_t)bucket * 128) * 64);

    int lane = threadIdx.x & 63;
    int rr   = lane >> 4;        // 0..3
    int c    = lane & 15;        // 0..15

    float4n acc = (float4n)(0.f);
    #pragma unroll
    for (int b = 0; b < 2; ++b) {
        float4n v[16];
        #pragma unroll
        for (int u = 0; u < 16; ++u)
            v[u] = __builtin_nontemporal_load(&base[(rr + (b * 16 + u) * 4) * 16 + c]);
        #pragma unroll
        for (int u = 0; u < 16; ++u)
            acc += v[u];
    }

    // reduce across the 4 row groups (lane bits 4,5)
    acc.x += __shfl_xor(acc.x, 16, 64);
    acc.y += __shfl_xor(acc.y, 16, 64);
    acc.z += __shfl_xor(acc.z, 16, 64);
    acc.w += __shfl_xor(acc.w, 16, 64);
    acc.x += __shfl_xor(acc.x, 32, 64);
    acc.y += __shfl_xor(acc.y, 32, 64);
    acc.z += __shfl_xor(acc.z, 32, 64);
    acc.w += __shfl_xor(acc.w, 32, 64);

    if (lane < 16) {
        acc *= (1.0f / 128.0f);
        float4n* dst = reinterpret_cast<float4n*>(
            sqk + (size_t)t * 32 * 64 * 64 + ((size_t)bh * 64 + bucket) * 64);
        dst[c] = acc;
    }
}

// ---------------------------------------------------------------------------
// Kernel B: per-bh  R = sq·sk^T/8, gumbel perturb, 8 sinkhorn iters, exp.
// grid.x = 32 (one block per bh), block = 1024 threads.
// Dot phase: wave w owns rows {w, w+16, w+32, w+48}; sq rows live in per-lane
// registers (global coalesced load) and are broadcast via v_readlane — only
// sk comes from LDS (1 ds_read per element instead of 5).
// ---------------------------------------------------------------------------
__global__ __launch_bounds__(1024) void sinkhorn_kernel(
    const float* __restrict__ sqk,      // [2][32][64][64]
    const float* __restrict__ u_gumbel, // [32][64][64]
    float* __restrict__ out)            // [32][64][64]
{
    int bh  = blockIdx.x;
    int tid = threadIdx.x;

    __shared__ float sk_s[64][65];
    __shared__ float r_s[64][65];

    const float* sqp = sqk + (size_t)bh * 4096;
    const float* skp = sqk + (size_t)32 * 4096 + (size_t)bh * 4096;

    // stage sk into LDS (4096 elems / 1024 threads)
    #pragma unroll
    for (int t = 0; t < 4; ++t) {
        int idx = tid + 1024 * t;
        sk_s[idx >> 6][idx & 63] = skp[idx];
    }

    int lane = tid & 63;
    int i0   = tid >> 6;              // wave id 0..15 (uniform per wave)

    // sq rows for this wave, in registers: lane e holds sq[i][e]
    float sqr0 = sqp[(i0     ) * 64 + lane];
    float sqr1 = sqp[(i0 + 16) * 64 + lane];
    float sqr2 = sqp[(i0 + 32) * 64 + lane];
    float sqr3 = sqp[(i0 + 48) * 64 + lane];
    __syncthreads();

    {
        int j = lane;
        float acc0 = 0.f, acc1 = 0.f, acc2 = 0.f, acc3 = 0.f;
        #pragma unroll
        for (int e = 0; e < 64; ++e) {
            float s = sk_s[j][e];     // banks (j+e)%32: 2-way, free
            acc0 = fmaf(readlane_f(sqr0, e), s, acc0);
            acc1 = fmaf(readlane_f(sqr1, e), s, acc1);
            acc2 = fmaf(readlane_f(sqr2, e), s, acc2);
            acc3 = fmaf(readlane_f(sqr3, e), s, acc3);
        }
        const float scale = 0.125f;   // 64^-0.5
        const float invT  = 1.0f / 0.7f;
        float accs[4] = {acc0, acc1, acc2, acc3};
        #pragma unroll
        for (int t = 0; t < 4; ++t) {
            int i   = i0 + 16 * t;
            float R = accs[t] * scale;
            float rl = fmaxf(R, 0.f);
            float u  = u_gumbel[(size_t)bh * 4096 + i * 64 + j];
            float gm = -__logf(-__logf(u + EPSF) + EPSF);
            r_s[i][j] = (__logf(rl + EPSF) + gm) * invT;
        }
    }
    __syncthreads();

    // Sinkhorn: 8 x (LSE-normalize axis=2 rows, then axis=1 cols).
    // 16 lanes per row/col; thread owns 4 consecutive elems (lane16*4+t):
    // banks (rc + 4*lane16 + t)%32 -> 2-way, free. Shuffle groups xor 1,2,4,8.
    int lane16 = tid & 15;
    int rc     = tid >> 4;            // 0..63
    int cbase  = lane16 * 4;
    for (int it = 0; it < 8; ++it) {
        {   // axis=2: LSE over j within row rc
            float v0 = r_s[rc][cbase + 0], v1 = r_s[rc][cbase + 1];
            float v2 = r_s[rc][cbase + 2], v3 = r_s[rc][cbase + 3];
            float m = fmaxf(fmaxf(v0, v1), fmaxf(v2, v3));
            m = fmaxf(m, __shfl_xor(m, 1, 64));
            m = fmaxf(m, __shfl_xor(m, 2, 64));
            m = fmaxf(m, __shfl_xor(m, 4, 64));
            m = fmaxf(m, __shfl_xor(m, 8, 64));
            float s = __expf(v0 - m) + __expf(v1 - m)
                    + __expf(v2 - m) + __expf(v3 - m);
            s += __shfl_xor(s, 1, 64);
            s += __shfl_xor(s, 2, 64);
            s += __shfl_xor(s, 4, 64);
            s += __shfl_xor(s, 8, 64);
            float lse = m + __logf(s);
            r_s[rc][cbase + 0] = v0 - lse;
            r_s[rc][cbase + 1] = v1 - lse;
            r_s[rc][cbase + 2] = v2 - lse;
            r_s[rc][cbase + 3] = v3 - lse;
        }
        __syncthreads();
        {   // axis=1: LSE over i within column rc
            float v0 = r_s[cbase + 0][rc], v1 = r_s[cbase + 1][rc];
            float v2 = r_s[cbase + 2][rc], v3 = r_s[cbase + 3][rc];
            float m = fmaxf(fmaxf(v0, v1), fmaxf(v2, v3));
            m = fmaxf(m, __shfl_xor(m, 1, 64));
            m = fmaxf(m, __shfl_xor(m, 2, 64));
            m = fmaxf(m, __shfl_xor(m, 4, 64));
            m = fmaxf(m, __shfl_xor(m, 8, 64));
            float s = __expf(v0 - m) + __expf(v1 - m)
                    + __expf(v2 - m) + __expf(v3 - m);
            s += __shfl_xor(s, 1, 64);
            s += __shfl_xor(s, 2, 64);
            s += __shfl_xor(s, 4, 64);
            s += __shfl_xor(s, 8, 64);
            float lse = m + __logf(s);
            r_s[cbase + 0][rc] = v0 - lse;
            r_s[cbase + 1][rc] = v1 - lse;
            r_s[cbase + 2][rc] = v2 - lse;
            r_s[cbase + 3][rc] = v3 - lse;
        }
        __syncthreads();
    }

    // out = exp(r)
    #pragma unroll
    for (int t = 0; t < 4; ++t) {
        int idx = tid + 1024 * t;
        out[(size_t)bh * 4096 + idx] = __expf(r_s[idx >> 6][idx & 63]);
    }
}

extern "C" void kernel_launch(void* const* d_in, const int* in_sizes, int n_in,
                              void* d_out, int out_size, void* d_ws, size_t ws_size,
                              hipStream_t stream) {
    const float* q = (const float*)d_in[0];        // [32,8192,64]
    const float* k = (const float*)d_in[1];        // [32,8192,64]
    const float* u = (const float*)d_in[2];        // [32,64,64]
    float* out = (float*)d_out;                    // [32,64,64]
    float* sqk = (float*)d_ws;                     // [2][32][64][64] = 1 MiB

    bucket_mean_kernel<<<1024, 256, 0, stream>>>(q, k, sqk);
    sinkhorn_kernel<<<32, 1024, 0, stream>>>(sqk, u, out);
}